// Round 5
// baseline (89.646 us; speedup 1.0000x reference)
//
#include <hip/hip_runtime.h>
#include <math.h>

#define PI_F 3.14159265358979323846f

// ev_w(x) is multilinear in b_k = (1, cos x_k, sin x_k) per wire:
// probabilities are quadratic in the initial per-wire factors (cos(x/2), sin(x/2)),
// and c^2=(1+cos x)/2, s^2=(1-cos x)/2, cs=sin(x)/2. So
//   ev_w = sum_{t0..t3} T[w,t0,t1,t2,t3] b0[t0] b1[t1] b2[t2] b3[t3]
// with a batch-uniform (4,3,3,3,3) coefficient tensor. gate_prep builds T by
// evaluating the (previously harness-verified) circuit at the 81 grid points
// {0, pi, pi/2}^4 and applying the exact per-axis inverse transform:
//   v(0)=a0+a1, v(pi)=a0-a1, v(pi/2)=a0+a2.
// Main kernel: 4 sincos + 324-coeff contraction, coefficients streamed as
// s_load via an addrspace(4) constant pointer (SGPR operands, zero VMEM).

typedef __attribute__((address_space(4))) const float cfloat;

__global__ void gate_prep(const float* __restrict__ params, float* __restrict__ g) {
    __shared__ float L[324];  // L[w*81 + i], i = ((t0*3+t1)*3+t2)*3+t3
    const int tid = threadIdx.x;

    if (tid < 81) {
        const int t3 = tid % 3, t2 = (tid / 3) % 3, t1 = (tid / 9) % 3, t0 = tid / 27;
        const float xg[3] = {0.f, PI_F, 0.5f * PI_F};
        const float xs[4] = {xg[t0], xg[t1], xg[t2], xg[t3]};

        // Full 16-amplitude complex sim at this grid point (round-2-verified math).
        float zr[16], zi[16];
        {
            float c[4], s[4];
            for (int k = 0; k < 4; ++k) { c[k] = cosf(0.5f * xs[k]); s[k] = sinf(0.5f * xs[k]); }
            for (int i = 0; i < 16; ++i) {
                zr[i] = ((i & 8) ? s[0] : c[0]) * ((i & 4) ? s[1] : c[1]) *
                        ((i & 2) ? s[2] : c[2]) * ((i & 1) ? s[3] : c[3]);
                zi[i] = 0.f;
            }
        }
        for (int layer = 0; layer < 2; ++layer) {
            for (int w = 0; w < 4; ++w) {
                const float p0 = params[(layer * 4 + w) * 2 + 0];  // RZ
                const float p1 = params[(layer * 4 + w) * 2 + 1];  // RX
                const float cz = cosf(0.5f * p0), sz = sinf(0.5f * p0);
                const float cx = cosf(0.5f * p1), sx = sinf(0.5f * p1);
                const float u00r = cx * cz,  u00i = -cx * sz;
                const float u01r = sx * sz,  u01i = -sx * cz;
                const float u10r = -sx * sz, u10i = -sx * cz;
                const float u11r = cx * cz,  u11i = cx * sz;
                const int M = 8 >> w;
                for (int i = 0; i < 16; ++i) {
                    if (!(i & M)) {
                        const int j = i | M;
                        const float ar = zr[i], ai = zi[i], br = zr[j], bi = zi[j];
                        zr[i] = u00r * ar - u00i * ai + u01r * br - u01i * bi;
                        zi[i] = u00r * ai + u00i * ar + u01r * bi + u01i * br;
                        zr[j] = u10r * ar - u10i * ai + u11r * br - u11i * bi;
                        zi[j] = u10r * ai + u10i * ar + u11r * bi + u11i * br;
                    }
                }
            }
            const int cm[4] = {8, 4, 2, 1}, tmm[4] = {4, 2, 1, 8};
            for (int kk = 0; kk < 4; ++kk)
                for (int i = 0; i < 16; ++i)
                    if ((i & cm[kk]) && !(i & tmm[kk])) {
                        const int j = i | tmm[kk];
                        float t;
                        t = zr[i]; zr[i] = zr[j]; zr[j] = t;
                        t = zi[i]; zi[i] = zi[j]; zi[j] = t;
                    }
        }
        float p[16];
        for (int i = 0; i < 16; ++i) p[i] = zr[i] * zr[i] + zi[i] * zi[i];
        const int wm[4] = {8, 4, 2, 1};
        for (int w = 0; w < 4; ++w) {
            float e = 0.f;
            for (int i = 0; i < 16; ++i) e += (i & wm[w]) ? -p[i] : p[i];
            L[w * 81 + tid] = e;
        }
    }
    __syncthreads();

    // Exact inverse transform along each base-3 digit (disjoint triples per pass).
    const int strides[4] = {27, 9, 3, 1};
    for (int d = 0; d < 4; ++d) {
        const int S = strides[d];
        if (tid < 108) {
            const int w = tid & 3, grp = tid >> 2;
            const int base = w * 81 + (grp / S) * (3 * S) + (grp % S);
            const float v0 = L[base], v1 = L[base + S], v2 = L[base + 2 * S];
            const float a0 = 0.5f * (v0 + v1);
            const float a1 = 0.5f * (v0 - v1);
            L[base] = a0;
            L[base + S] = a1;
            L[base + 2 * S] = v2 - a0;
        }
        __syncthreads();
    }

    // Output layout: g[i*4 + w] = T[w, t0,t1,t2,t3]  (36 contiguous per (t0,t1))
    for (int k = tid; k < 324; k += blockDim.x) {
        g[k] = L[(k & 3) * 81 + (k >> 2)];
    }
}

__global__ __launch_bounds__(256) void qsim_kernel(const float* __restrict__ x,
                                                   const float* __restrict__ gf,
                                                   float* __restrict__ out, int batch) {
    const int b = blockIdx.x * 256 + threadIdx.x;
    if (b >= batch) return;

    cfloat* T = (cfloat*)gf;  // constant addrspace -> s_load -> SGPR operands

    const float4 xv = reinterpret_cast<const float4*>(x)[b];
    float c[4], s[4];
    __sincosf(xv.x, &s[0], &c[0]);
    __sincosf(xv.y, &s[1], &c[1]);
    __sincosf(xv.z, &s[2], &c[2]);
    __sincosf(xv.w, &s[3], &c[3]);

    // u[p], p = t2*3+t3: products of b2[t2]*b3[t3]; u[0]=1 handled implicitly.
    float u[9];
    u[1] = c[3];        u[2] = s[3];
    u[3] = c[2];        u[6] = s[2];
    u[4] = c[2] * c[3]; u[5] = c[2] * s[3];
    u[7] = s[2] * c[3]; u[8] = s[2] * s[3];

    float ev[4];
#pragma unroll
    for (int t0 = 0; t0 < 3; ++t0) {
        float o1[4];
#pragma unroll
        for (int t1 = 0; t1 < 3; ++t1) {
            cfloat* Tp = T + (t0 * 3 + t1) * 36;
            float inner[4];
#pragma unroll
            for (int w = 0; w < 4; ++w) inner[w] = Tp[w];  // p=0 term (u=1)
#pragma unroll
            for (int p = 1; p < 9; ++p)
#pragma unroll
                for (int w = 0; w < 4; ++w)
                    inner[w] = fmaf(u[p], Tp[p * 4 + w], inner[w]);

            if (t1 == 0) {
#pragma unroll
                for (int w = 0; w < 4; ++w) o1[w] = inner[w];
            } else if (t1 == 1) {
#pragma unroll
                for (int w = 0; w < 4; ++w) o1[w] = fmaf(c[1], inner[w], o1[w]);
            } else {
#pragma unroll
                for (int w = 0; w < 4; ++w) o1[w] = fmaf(s[1], inner[w], o1[w]);
            }
        }
        if (t0 == 0) {
#pragma unroll
            for (int w = 0; w < 4; ++w) ev[w] = o1[w];
        } else if (t0 == 1) {
#pragma unroll
            for (int w = 0; w < 4; ++w) ev[w] = fmaf(c[0], o1[w], ev[w]);
        } else {
#pragma unroll
            for (int w = 0; w < 4; ++w) ev[w] = fmaf(s[0], o1[w], ev[w]);
        }
    }

    reinterpret_cast<float4*>(out)[b] = make_float4(ev[0], ev[1], ev[2], ev[3]);
}

extern "C" void kernel_launch(void* const* d_in, const int* in_sizes, int n_in,
                              void* d_out, int out_size, void* d_ws, size_t ws_size,
                              hipStream_t stream) {
    const float* x = (const float*)d_in[0];        // (B, 4) float32
    const float* params = (const float*)d_in[1];   // (2, 4, 2) float32
    float* out = (float*)d_out;                    // (B, 4) float32
    float* g = (float*)d_ws;                       // 324 floats: T tensor
    const int batch = in_sizes[0] / 4;

    gate_prep<<<1, 128, 0, stream>>>(params, g);
    const int blocks = (batch + 255) / 256;
    qsim_kernel<<<blocks, 256, 0, stream>>>(x, g, out, batch);
}